// Round 6
// baseline (1736.012 us; speedup 1.0000x reference)
//
#include <hip/hip_runtime.h>

#define BATCH   8
#define NPTS    8192
#define NPOINT  1024
#define NSAMPLE 32
#define CHANC   32
#define OUTC    35          // 3 xyz + 32 point channels
#define R2      0.0625f     // 0.25^2

typedef float v2f __attribute__((ext_vector_type(2)));

// DPP helpers --------------------------------------------------------------
template <int CTRL>
__device__ __forceinline__ float dpp_max_step(float v) {
    int r = __builtin_amdgcn_update_dpp(__float_as_int(v), __float_as_int(v),
                                        CTRL, 0xf, 0xf, false);
    return fmaxf(v, __int_as_float(r));
}
#define DPP_ROW_SHR(n)  (0x110 | (n))
#define DPP_BCAST15     0x142
#define DPP_BCAST31     0x143

// ---------------------------------------------------------------------------
// Kernel 1: furthest point sampling. 4 blocks x 512 threads; each block runs
// TWO independent batches (team = 4 waves, 256 threads, 32 pts/thread in
// registers). Co-residency de-correlates the two teams' barrier/LDS stall
// chains on each SIMD, and the bigger tile amortizes reduction overhead.
// Bit-exact fp32 (contract off). Argmax: inline per-thread tracking ->
// DPP wave max -> ballot leader -> packed u64 (val<<32|~idx) partial ->
// block barrier -> 4-slot scan (u64 max handles exact tie->lowest index).
// Winner coords: 3 uniform global loads (L2-resident xyz), no LDS mirror.
// ---------------------------------------------------------------------------
__global__ __launch_bounds__(512) void fps_kernel(const float* __restrict__ xyz,
                                                  float* __restrict__ new_xyz) {
#pragma clang fp contract(off)
    const int t    = threadIdx.x;
    const int team = t >> 8;             // 0 or 1
    const int tt   = t & 255;            // thread within team
    const int lane = t & 63;
    const int w    = (t >> 6) & 3;       // wave within team, 0..3
    const int b    = blockIdx.x * 2 + team;
    const float* bx = xyz + (size_t)b * NPTS * 3;

    __shared__ unsigned long long partial[2][2][4];   // [parity][team][wave]

    // thread tt owns points j = tt*32 + i, i in [0,32): 96 consecutive floats
    v2f px[16], py[16], pz[16], dist[16];
    {
        float f[96];
        float4* fq = (float4*)f;
        const float4* s4 = (const float4*)bx + tt * 24;
#pragma unroll
        for (int q = 0; q < 24; ++q) fq[q] = s4[q];
#pragma unroll
        for (int p = 0; p < 16; ++p) {
            px[p] = (v2f){f[6 * p + 0], f[6 * p + 3]};
            py[p] = (v2f){f[6 * p + 1], f[6 * p + 4]};
            pz[p] = (v2f){f[6 * p + 2], f[6 * p + 5]};
            dist[p] = (v2f){1e38f, 1e38f};
        }
    }

    // seed: xyz[b, 0]
    float lx = bx[0], ly = bx[1], lz = bx[2];
    if (tt == 0) {
        float* o = new_xyz + (size_t)b * NPOINT * 3;
        o[0] = lx; o[1] = ly; o[2] = lz;
    }

    for (int s = 1; s < NPOINT; ++s) {
        // --- packed update + inline argmax over this thread's 32 points ---
        const v2f lx2 = (v2f){lx, lx};
        const v2f ly2 = (v2f){ly, ly};
        const v2f lz2 = (v2f){lz, lz};
        float bestv = -1.0f;
        int   bi    = 0;
#pragma unroll
        for (int p = 0; p < 16; ++p) {
            const v2f dx = px[p] - lx2;
            const v2f dy = py[p] - ly2;
            const v2f dz = pz[p] - lz2;
            const v2f d2 = (dx * dx + dy * dy) + dz * dz;   // contract off -> exact
            const float d0 = fminf(dist[p].x, d2.x);
            const float d1 = fminf(dist[p].y, d2.y);
            dist[p] = (v2f){d0, d1};
            if (d0 > bestv) { bestv = d0; bi = 2 * p; }     // strict > keeps lowest i
            if (d1 > bestv) { bestv = d1; bi = 2 * p + 1; }
        }
        const int besti = (tt << 5) + bi;   // ascending with lane & wave order

        // --- wave64 max via DPP (no LDS) ---
        float v = bestv;
        v = dpp_max_step<DPP_ROW_SHR(1)>(v);
        v = dpp_max_step<DPP_ROW_SHR(2)>(v);
        v = dpp_max_step<DPP_ROW_SHR(4)>(v);
        v = dpp_max_step<DPP_ROW_SHR(8)>(v);
        v = dpp_max_step<DPP_BCAST15>(v);
        v = dpp_max_step<DPP_BCAST31>(v);
        const float smax = __int_as_float(__builtin_amdgcn_readlane(__float_as_int(v), 63));

        // leader lane (lowest lane holding max == lowest index) writes partial
        const unsigned long long m = __ballot(bestv == smax);
        const int par = s & 1;
        if (lane == (int)__builtin_ctzll(m)) {
            partial[par][team][w] = ((unsigned long long)__float_as_uint(smax) << 32)
                                    | (unsigned)(~besti);
        }
        __syncthreads();

        // --- all lanes of the team scan its 4 partials (broadcast reads) ---
        unsigned long long bp = partial[par][team][0];
#pragma unroll
        for (int q = 1; q < 4; ++q) {
            const unsigned long long o = partial[par][team][q];
            if (o > bp) bp = o;
        }
        const int idx = (int)(~(unsigned)bp);

        // winner coords: uniform global loads, L2-resident
        const float* wp = bx + idx * 3;
        lx = wp[0]; ly = wp[1]; lz = wp[2];
        if (tt == 0) {
            float* o = new_xyz + ((size_t)b * NPOINT + s) * 3;
            o[0] = lx; o[1] = ly; o[2] = lz;
        }
    }
}

// ---------------------------------------------------------------------------
// Kernel 2: ball query + grouping. One wave per center (8192 waves).
// x2 unrolled ballot loop (128 points per round, loads hoisted); ordered
// first-NSAMPLE collection, padded with first hit; coalesced 32x35 store.
// ---------------------------------------------------------------------------
__global__ __launch_bounds__(256) void ballgroup_kernel(const float* __restrict__ xyz,
                                                        const float* __restrict__ points,
                                                        const float* __restrict__ new_xyz,
                                                        float* __restrict__ out) {
#pragma clang fp contract(off)
    const int lane = threadIdx.x & 63;
    const int w    = threadIdx.x >> 6;
    const int gw   = blockIdx.x * 4 + w;      // center id, 0..8191
    const int b    = gw >> 10;

    const float* bx  = xyz + (size_t)b * NPTS * 3;
    const float* cen = new_xyz + (size_t)gw * 3;
    const float cx = cen[0], cy = cen[1], cz = cen[2];

    __shared__ int idxbuf[4][NSAMPLE];

    int k = 0;
    for (int base = 0; base < NPTS; base += 128) {
        const int j0 = base + lane;
        const int j1 = j0 + 64;
        // hoist all 6 loads so they pipeline
        const float a0 = bx[j0 * 3 + 0], a1 = bx[j0 * 3 + 1], a2 = bx[j0 * 3 + 2];
        const float c0 = bx[j1 * 3 + 0], c1 = bx[j1 * 3 + 1], c2 = bx[j1 * 3 + 2];
        const float dxa = a0 - cx, dya = a1 - cy, dza = a2 - cz;
        const float d2a = (dxa * dxa + dya * dya) + dza * dza;   // contract off
        const float dxb = c0 - cx, dyb = c1 - cy, dzb = c2 - cz;
        const float d2b = (dxb * dxb + dyb * dyb) + dzb * dzb;
        const bool inA = d2a < R2;
        const bool inB = d2b < R2;

        const unsigned long long mA = __ballot(inA);
        int pre = __popcll(mA & ((1ull << lane) - 1ull));
        if (inA && (k + pre) < NSAMPLE) idxbuf[w][k + pre] = j0;
        k += __popcll(mA);
        if (k >= NSAMPLE) { k = NSAMPLE; break; }        // k is wave-uniform

        const unsigned long long mB = __ballot(inB);
        pre = __popcll(mB & ((1ull << lane) - 1ull));
        if (inB && (k + pre) < NSAMPLE) idxbuf[w][k + pre] = j1;
        k += __popcll(mB);
        if (k >= NSAMPLE) { k = NSAMPLE; break; }
    }
    // center is itself one of the points (d2 == 0), so k >= 1 always.
    const int first = idxbuf[w][0];

    float*       o    = out + (size_t)gw * NSAMPLE * OUTC;
    const float* prow = points + (size_t)b * NPTS * CHANC;
    for (int e = lane; e < NSAMPLE * OUTC; e += 64) {
        const int s = e / OUTC;
        const int c = e - s * OUTC;
        const int j = (s < k) ? idxbuf[w][s] : first;
        float v;
        if (c < 3) {
            const float cc = (c == 0) ? cx : (c == 1) ? cy : cz;
            v = bx[j * 3 + c] - cc;
        } else {
            v = prow[j * CHANC + (c - 3)];
        }
        o[e] = v;   // consecutive lanes -> consecutive addresses (coalesced)
    }
}

// ---------------------------------------------------------------------------
extern "C" void kernel_launch(void* const* d_in, const int* in_sizes, int n_in,
                              void* d_out, int out_size, void* d_ws, size_t ws_size,
                              hipStream_t stream) {
    const float* xyz    = (const float*)d_in[0];   // (8, 8192, 3)  fp32
    const float* points = (const float*)d_in[1];   // (8, 8192, 32) fp32
    float* new_xyz    = (float*)d_out;                         // (8,1024,3)
    float* new_points = new_xyz + (size_t)BATCH * NPOINT * 3;  // (8,1024,32,35)

    fps_kernel<<<BATCH / 2, 512, 0, stream>>>(xyz, new_xyz);
    ballgroup_kernel<<<(BATCH * NPOINT) / 4, 256, 0, stream>>>(xyz, points, new_xyz, new_points);
}

// Round 7
// 1122.304 us; speedup vs baseline: 1.5468x; 1.5468x over previous
//
#include <hip/hip_runtime.h>

#define BATCH   8
#define NPTS    8192
#define NPOINT  1024
#define NSAMPLE 32
#define CHANC   32
#define OUTC    35          // 3 xyz + 32 point channels
#define R2      0.0625f     // 0.25^2

typedef float v2f __attribute__((ext_vector_type(2)));

// DPP helpers --------------------------------------------------------------
template <int CTRL>
__device__ __forceinline__ float dpp_max_step(float v) {
    int r = __builtin_amdgcn_update_dpp(__float_as_int(v), __float_as_int(v),
                                        CTRL, 0xf, 0xf, false);
    return fmaxf(v, __int_as_float(r));
}
#define DPP_ROW_SHR(n)  (0x110 | (n))
#define DPP_BCAST15     0x142
#define DPP_BCAST31     0x143

// ---------------------------------------------------------------------------
// Kernel 1: furthest point sampling. One block per batch, 512 threads,
// 16 contiguous points per thread (j = t*16+i; VGPR-pressure sweet spot —
// 32/thread spills, round-6 evidence). Bit-exact fp32 (contract off),
// packed-f32 distance update. Wave argmax: DPP max + readlane(63) + ballot
// leader. Leaders write f32 value + int index partials (separate arrays).
// One barrier/iter (parity double-buffer). Post-barrier scan: 2x ds_read_b128
// (broadcast) + max3 tree + equality mask + ctz -> slot; 1x ds_read_b32 for
// index; winner coords from XOR-swizzled float4 LDS mirror (broadcast b128).
// LDS-pipe ops per wave-iter: 4 (was 9) — the LDS pipe was the hidden cost.
// ---------------------------------------------------------------------------
__global__ __launch_bounds__(512) void fps_kernel(const float* __restrict__ xyz,
                                                  float* __restrict__ new_xyz) {
#pragma clang fp contract(off)
    const int b    = blockIdx.x;
    const int t    = threadIdx.x;
    const int lane = t & 63;
    const int w    = t >> 6;              // wave id, 0..7
    const float* bx = xyz + (size_t)b * NPTS * 3;

    __shared__ float4 pts[NPTS];                         // 128 KB, XOR-swizzled
    __shared__ __align__(16) float pv[2][8];             // [parity][wave] value
    __shared__ __align__(16) int   pi[2][8];             // [parity][wave] index

    // thread t owns points j = t*16 + i, i in [0,16): 48 consecutive floats
    v2f px[8], py[8], pz[8], dist[8];
    {
        float f[48];
        float4* fq = (float4*)f;
        const float4* s4 = (const float4*)bx + t * 12;
#pragma unroll
        for (int q = 0; q < 12; ++q) fq[q] = s4[q];
#pragma unroll
        for (int p = 0; p < 8; ++p) {
            px[p] = (v2f){f[6 * p + 0], f[6 * p + 3]};
            py[p] = (v2f){f[6 * p + 1], f[6 * p + 4]};
            pz[p] = (v2f){f[6 * p + 2], f[6 * p + 5]};
            dist[p] = (v2f){1e38f, 1e38f};
        }
#pragma unroll
        for (int i = 0; i < 16; ++i) {
            const int j  = t * 16 + i;
            const int js = j ^ ((j >> 4) & 7);      // bank swizzle
            pts[js] = make_float4(f[3 * i + 0], f[3 * i + 1], f[3 * i + 2], 0.0f);
        }
    }
    __syncthreads();

    // seed: xyz[b, 0]  (swizzle(0) == 0)
    float4 c0 = pts[0];
    float lx = c0.x, ly = c0.y, lz = c0.z;
    if (t == 0) {
        float* o = new_xyz + (size_t)b * NPOINT * 3;
        o[0] = lx; o[1] = ly; o[2] = lz;
    }

    for (int s = 1; s < NPOINT; ++s) {
        // --- packed update + argmax over this thread's 16 points ---
        const v2f lx2 = (v2f){lx, lx};
        const v2f ly2 = (v2f){ly, ly};
        const v2f lz2 = (v2f){lz, lz};
        float bestv = -1.0f;
        int   bi    = 0;
#pragma unroll
        for (int p = 0; p < 8; ++p) {
            const v2f dx = px[p] - lx2;
            const v2f dy = py[p] - ly2;
            const v2f dz = pz[p] - lz2;
            const v2f d2 = (dx * dx + dy * dy) + dz * dz;   // contract off -> exact
            const float d0 = fminf(dist[p].x, d2.x);
            const float d1 = fminf(dist[p].y, d2.y);
            dist[p] = (v2f){d0, d1};
            if (d0 > bestv) { bestv = d0; bi = 2 * p; }     // strict > keeps lowest i
            if (d1 > bestv) { bestv = d1; bi = 2 * p + 1; }
        }
        const int besti = (t << 4) + bi;

        // --- wave64 max via DPP (no LDS) ---
        float v = bestv;
        v = dpp_max_step<DPP_ROW_SHR(1)>(v);
        v = dpp_max_step<DPP_ROW_SHR(2)>(v);
        v = dpp_max_step<DPP_ROW_SHR(4)>(v);
        v = dpp_max_step<DPP_ROW_SHR(8)>(v);
        v = dpp_max_step<DPP_BCAST15>(v);
        v = dpp_max_step<DPP_BCAST31>(v);
        const float smax = __int_as_float(__builtin_amdgcn_readlane(__float_as_int(v), 63));

        // leader lane (lowest lane holding the max == lowest index) writes partials
        const unsigned long long m = __ballot(bestv == smax);
        const int par = s & 1;
        if (lane == (int)__builtin_ctzll(m)) {
            pv[par][w] = smax;
            pi[par][w] = besti;
        }
        __syncthreads();

        // --- all lanes scan the 8 partials: 2x b128 broadcast + max3 tree ---
        const float4* pvq = (const float4*)pv[par];
        const float4 a = pvq[0];
        const float4 c = pvq[1];
        const float M = fmaxf(fmaxf(fmaxf(a.x, a.y), fmaxf(a.z, a.w)),
                              fmaxf(fmaxf(c.x, c.y), fmaxf(c.z, c.w)));
        const unsigned mask = (unsigned)(a.x == M)        | ((unsigned)(a.y == M) << 1)
                            | ((unsigned)(a.z == M) << 2) | ((unsigned)(a.w == M) << 3)
                            | ((unsigned)(c.x == M) << 4) | ((unsigned)(c.y == M) << 5)
                            | ((unsigned)(c.z == M) << 6) | ((unsigned)(c.w == M) << 7);
        const int slot = __builtin_ctz(mask);   // lowest wave == lowest global index
        const int idx  = pi[par][slot];         // uniform -> broadcast read

        const int js = idx ^ ((idx >> 4) & 7);
        const float4 cw = pts[js];              // uniform -> broadcast b128
        lx = cw.x; ly = cw.y; lz = cw.z;
        if (t == 0) {
            float* o = new_xyz + ((size_t)b * NPOINT + s) * 3;
            o[0] = lx; o[1] = ly; o[2] = lz;
        }
    }
}

// ---------------------------------------------------------------------------
// Kernel 2: ball query + grouping. One wave per center (8192 waves).
// x2 unrolled ballot loop (128 points per round, loads hoisted); ordered
// first-NSAMPLE collection, padded with first hit; coalesced 32x35 store.
// ---------------------------------------------------------------------------
__global__ __launch_bounds__(256) void ballgroup_kernel(const float* __restrict__ xyz,
                                                        const float* __restrict__ points,
                                                        const float* __restrict__ new_xyz,
                                                        float* __restrict__ out) {
#pragma clang fp contract(off)
    const int lane = threadIdx.x & 63;
    const int w    = threadIdx.x >> 6;
    const int gw   = blockIdx.x * 4 + w;      // center id, 0..8191
    const int b    = gw >> 10;

    const float* bx  = xyz + (size_t)b * NPTS * 3;
    const float* cen = new_xyz + (size_t)gw * 3;
    const float cx = cen[0], cy = cen[1], cz = cen[2];

    __shared__ int idxbuf[4][NSAMPLE];

    int k = 0;
    for (int base = 0; base < NPTS; base += 128) {
        const int j0 = base + lane;
        const int j1 = j0 + 64;
        // hoist all 6 loads so they pipeline
        const float a0 = bx[j0 * 3 + 0], a1 = bx[j0 * 3 + 1], a2 = bx[j0 * 3 + 2];
        const float c0 = bx[j1 * 3 + 0], c1 = bx[j1 * 3 + 1], c2 = bx[j1 * 3 + 2];
        const float dxa = a0 - cx, dya = a1 - cy, dza = a2 - cz;
        const float d2a = (dxa * dxa + dya * dya) + dza * dza;   // contract off
        const float dxb = c0 - cx, dyb = c1 - cy, dzb = c2 - cz;
        const float d2b = (dxb * dxb + dyb * dyb) + dzb * dzb;
        const bool inA = d2a < R2;
        const bool inB = d2b < R2;

        const unsigned long long mA = __ballot(inA);
        int pre = __popcll(mA & ((1ull << lane) - 1ull));
        if (inA && (k + pre) < NSAMPLE) idxbuf[w][k + pre] = j0;
        k += __popcll(mA);
        if (k >= NSAMPLE) { k = NSAMPLE; break; }        // k is wave-uniform

        const unsigned long long mB = __ballot(inB);
        pre = __popcll(mB & ((1ull << lane) - 1ull));
        if (inB && (k + pre) < NSAMPLE) idxbuf[w][k + pre] = j1;
        k += __popcll(mB);
        if (k >= NSAMPLE) { k = NSAMPLE; break; }
    }
    // center is itself one of the points (d2 == 0), so k >= 1 always.
    const int first = idxbuf[w][0];

    float*       o    = out + (size_t)gw * NSAMPLE * OUTC;
    const float* prow = points + (size_t)b * NPTS * CHANC;
    for (int e = lane; e < NSAMPLE * OUTC; e += 64) {
        const int s = e / OUTC;
        const int c = e - s * OUTC;
        const int j = (s < k) ? idxbuf[w][s] : first;
        float v;
        if (c < 3) {
            const float cc = (c == 0) ? cx : (c == 1) ? cy : cz;
            v = bx[j * 3 + c] - cc;
        } else {
            v = prow[j * CHANC + (c - 3)];
        }
        o[e] = v;   // consecutive lanes -> consecutive addresses (coalesced)
    }
}

// ---------------------------------------------------------------------------
extern "C" void kernel_launch(void* const* d_in, const int* in_sizes, int n_in,
                              void* d_out, int out_size, void* d_ws, size_t ws_size,
                              hipStream_t stream) {
    const float* xyz    = (const float*)d_in[0];   // (8, 8192, 3)  fp32
    const float* points = (const float*)d_in[1];   // (8, 8192, 32) fp32
    float* new_xyz    = (float*)d_out;                         // (8,1024,3)
    float* new_points = new_xyz + (size_t)BATCH * NPOINT * 3;  // (8,1024,32,35)

    fps_kernel<<<BATCH, 512, 0, stream>>>(xyz, new_xyz);
    ballgroup_kernel<<<(BATCH * NPOINT) / 4, 256, 0, stream>>>(xyz, points, new_xyz, new_points);
}